// Round 1
// 585.983 us; speedup vs baseline: 1.3338x; 1.3338x over previous
//
#include <hip/hip_runtime.h>
#include <hip/hip_bf16.h>

// LSTM cell, R4: split into (1) one-time fp32->bf16 conversion passes into d_ws
// (Acat=[X|Hx] 4096x4096, Bcat=[Wx|Wh] 8192x4096 with gate-interleaved rows
// j'=4h+g), and (2) an m97-structure bf16 GEMM: global_load_lds width=16,
// linear LDS [128][64], XOR slot-swizzle applied via pre-swizzled global source
// addresses (gload_lds dest must be linear) and on ds_read -> conflict-free
// fragment reads. Epilogue (bias + activations + shfl gate exchange) unchanged.
// Fallback to the R3 register-staging kernel if ws_size < ~96MB.

#define BATCH 4096
#define HID   2048
#define KDIM  2048
#define K4    4096    // fused K = INPUT_SIZE + HIDDEN_SIZE
#define BM    128
#define BK    64
#define LDK   72      // fallback kernel's padded LDS stride

typedef __attribute__((ext_vector_type(8))) short  short8;
typedef __attribute__((ext_vector_type(4))) float  f32x4;

__device__ __forceinline__ float sigm(float x)  { return 1.f / (1.f + __expf(-x)); }
__device__ __forceinline__ float tanhx(float x) { return 2.f / (1.f + __expf(-2.f * x)) - 1.f; }

__device__ __forceinline__ uint2 pk_bf16x4(float4 v) {
  __hip_bfloat162 lo = __float22bfloat162_rn(make_float2(v.x, v.y));
  __hip_bfloat162 hi = __float22bfloat162_rn(make_float2(v.z, v.w));
  uint2 r;
  r.x = *(unsigned*)&lo;
  r.y = *(unsigned*)&hi;
  return r;
}

__device__ __forceinline__ void gload16(const void* g, void* l) {
  __builtin_amdgcn_global_load_lds(
      (const __attribute__((address_space(1))) unsigned int*)g,
      (__attribute__((address_space(3))) unsigned int*)l, 16, 0, 0);
}

// ---------------- conversion pass 1: Acat = bf16([X | Hx]) ------------------
__global__ __launch_bounds__(256) void conv_a(const float* __restrict__ X,
                                              const float* __restrict__ Hx,
                                              short* __restrict__ A) {
  const int gid = blockIdx.x * 256 + threadIdx.x;   // one 8-elem chunk each
  const int m   = gid >> 9;                         // 512 chunks per 4096-row
  const int pos = (gid & 511) << 3;
  const float* src = (pos < KDIM) ? X  + (size_t)m * KDIM + pos
                                  : Hx + (size_t)m * KDIM + (pos - KDIM);
  float4 v0 = *(const float4*)src;
  float4 v1 = *(const float4*)(src + 4);
  uint2 p0 = pk_bf16x4(v0), p1 = pk_bf16x4(v1);
  uint4 o; o.x = p0.x; o.y = p0.y; o.z = p1.x; o.w = p1.y;
  *(uint4*)(A + (size_t)gid * 8) = o;
}

// ------ conversion pass 2: Bcat[j'=4h+g][k] = bf16([Wx | Wh][g*2048+h]) -----
__global__ __launch_bounds__(256) void conv_b(const float* __restrict__ Wx,
                                              const float* __restrict__ Wh,
                                              short* __restrict__ Bm) {
  const int gid = blockIdx.x * 256 + threadIdx.x;
  const int jp  = gid >> 9;                         // j' = 4*h + gate
  const int pos = (gid & 511) << 3;
  const int srow = (jp & 3) * HID + (jp >> 2);      // gate*2048 + h
  const float* src = (pos < KDIM) ? Wx + (size_t)srow * KDIM + pos
                                  : Wh + (size_t)srow * KDIM + (pos - KDIM);
  float4 v0 = *(const float4*)src;
  float4 v1 = *(const float4*)(src + 4);
  uint2 p0 = pk_bf16x4(v0), p1 = pk_bf16x4(v1);
  uint4 o; o.x = p0.x; o.y = p0.y; o.z = p1.x; o.w = p1.y;
  *(uint4*)(Bm + (size_t)gid * 8) = o;
}

// ---------------- main GEMM + LSTM epilogue (m97 structure) -----------------
__global__ __launch_bounds__(256) void lstm_mm(
    const short* __restrict__ A, const short* __restrict__ Bm,
    const float* __restrict__ Cx,
    const float* __restrict__ bx, const float* __restrict__ bh,
    float* __restrict__ Hy, float* __restrict__ Cy)
{
  __shared__ __align__(16) short A_lds[BM * BK];    // [m][k] linear, swizzled slots
  __shared__ __align__(16) short B_lds[BM * BK];    // [c][k] linear, swizzled slots

  const int tid  = threadIdx.x;
  const int wv   = tid >> 6;
  const int lane = tid & 63;
  const int quad = lane >> 4;
  const int ln   = lane & 15;
  const int wm   = wv >> 1;
  const int wn   = wv & 1;
  const int m0   = blockIdx.x * BM;
  const int j0   = blockIdx.y * BM;                 // = 4 * h0
  const int h0   = blockIdx.y * 32;

  f32x4 acc[4][4];
  #pragma unroll
  for (int a = 0; a < 4; ++a)
    #pragma unroll
    for (int b = 0; b < 4; ++b)
      acc[a][b] = (f32x4){0.f, 0.f, 0.f, 0.f};

  // Staging: each wave fills rows [wv*32, wv*32+32) of both LDS tiles with
  // 4 gload16 issues per matrix (each issue = 8 rows x 128B, linear dest).
  // Swizzle: LDS slot p of row r holds global k-slot (p ^ (r&7)).
  const int srow = lane >> 3;                       // row within 8-row issue
  const int slot = lane & 7;                        // 16B slot within row
  const int sx   = ((slot ^ srow) << 3);            // pre-swizzled k element
  const short* ag = A  + (size_t)(m0 + wv * 32 + srow) * K4 + sx;
  const short* bg = Bm + (size_t)(j0 + wv * 32 + srow) * K4 + sx;
  short* al = &A_lds[wv * 32 * BK];
  short* bl = &B_lds[wv * 32 * BK];

  for (int t = 0; t < K4 / BK; ++t) {
    const int k0 = t * BK;
    __syncthreads();                                // prev tile's reads done
    #pragma unroll
    for (int i = 0; i < 4; ++i) {
      gload16(ag + k0 + i * 8 * K4, al + i * 8 * BK);
      gload16(bg + k0 + i * 8 * K4, bl + i * 8 * BK);
    }
    __syncthreads();                                // drains vmcnt: tile ready
    #pragma unroll
    for (int ks = 0; ks < 2; ++ks) {
      short8 af[4], bfv[4];
      #pragma unroll
      for (int u = 0; u < 4; ++u) {
        const int ar = wm * 64 + u * 16 + ln;
        af[u]  = *(const short8*)&A_lds[ar * BK + (((ks * 4 + quad) ^ (ar & 7)) << 3)];
      }
      #pragma unroll
      for (int u = 0; u < 4; ++u) {
        const int br = wn * 64 + u * 16 + ln;
        bfv[u] = *(const short8*)&B_lds[br * BK + (((ks * 4 + quad) ^ (br & 7)) << 3)];
      }
      #pragma unroll
      for (int tm = 0; tm < 4; ++tm)
        #pragma unroll
        for (int tn = 0; tn < 4; ++tn)
          acc[tm][tn] = __builtin_amdgcn_mfma_f32_16x16x32_bf16(
              af[tm], bfv[tn], acc[tm][tn], 0, 0, 0);
    }
  }

  // ---- epilogue: C/D layout col = lane&15 (c), row = quad*4 + reg ----
  const int g = lane & 3;                           // gate of this lane (c&3)
  float biasv[4];
  int   hgs[4];
  #pragma unroll
  for (int tn = 0; tn < 4; ++tn) {
    int c  = wn * 64 + tn * 16 + ln;
    int hg = h0 + (c >> 2);
    hgs[tn] = hg;
    int j = g * HID + hg;
    biasv[tn] = bx[j] + bh[j];
  }
  #pragma unroll
  for (int tm = 0; tm < 4; ++tm) {
    #pragma unroll
    for (int r = 0; r < 4; ++r) {
      int mrow = m0 + wm * 64 + tm * 16 + quad * 4 + r;
      #pragma unroll
      for (int tn = 0; tn < 4; ++tn) {
        float v   = acc[tm][tn][r] + biasv[tn];
        float act = (g == 2) ? tanhx(v) : sigm(v);
        float y1 = __shfl_xor(act, 1);
        float y2 = __shfl_xor(act, 2);
        float y3 = __shfl_xor(act, 3);
        float ft = (g == 0) ? act : ((g == 1) ? y1 : ((g == 2) ? y2 : y3));
        float it = (g == 1) ? act : ((g == 0) ? y1 : ((g == 3) ? y2 : y3));
        float gt = (g == 2) ? act : ((g == 3) ? y1 : ((g == 0) ? y2 : y3));
        float ot = (g == 3) ? act : ((g == 2) ? y1 : ((g == 1) ? y2 : y3));
        if (g < 2) {
          size_t off = (size_t)mrow * HID + hgs[tn];
          float cxv = Cx[off];
          float cyv = ft * cxv + it * gt;
          if (g == 0) Hy[off] = ot * tanhx(cyv);
          else        Cy[off] = cyv;
        }
      }
    }
  }
}

// ---------------- fallback: R3 kernel (register staging, fp32 in) ----------
__global__ __launch_bounds__(256) void lstm_cell_fallback(
    const float* __restrict__ X, const float* __restrict__ Hx,
    const float* __restrict__ Cx,
    const float* __restrict__ Wx, const float* __restrict__ bx,
    const float* __restrict__ Wh, const float* __restrict__ bh,
    float* __restrict__ Hy, float* __restrict__ Cy)
{
  __shared__ __align__(16) short A_lds[BM * LDK];
  __shared__ __align__(16) short B_lds[BM * LDK];

  const int tid  = threadIdx.x;
  const int wv   = tid >> 6;
  const int lane = tid & 63;
  const int quad = lane >> 4;
  const int ln   = lane & 15;
  const int wm   = wv >> 1;
  const int wn   = wv & 1;
  const int m0   = blockIdx.x * BM;
  const int h0   = blockIdx.y * 32;

  f32x4 acc[4][4];
  #pragma unroll
  for (int a = 0; a < 4; ++a)
    #pragma unroll
    for (int b = 0; b < 4; ++b)
      acc[a][b] = (f32x4){0.f, 0.f, 0.f, 0.f};

  const int rA  = tid >> 4;
  const int kc4 = (tid & 15) * 4;
  size_t aoff[8], boff[8];
  int    lrow[8];
  #pragma unroll
  for (int q = 0; q < 8; ++q) {
    int row  = q * 16 + rA;
    lrow[q]  = row;
    aoff[q]  = (size_t)(m0 + row) * KDIM + kc4;
    int wrow = (row & 3) * HID + h0 + (row >> 2);
    boff[q]  = (size_t)wrow * KDIM + kc4;
  }

  const int NT = 2 * (KDIM / BK);
  float4 areg[8], breg[8];
  #pragma unroll
  for (int q = 0; q < 8; ++q) {
    areg[q] = *(const float4*)(X  + aoff[q]);
    breg[q] = *(const float4*)(Wx + boff[q]);
  }

  for (int t = 0; t < NT; ++t) {
    __syncthreads();
    #pragma unroll
    for (int q = 0; q < 8; ++q) {
      *(uint2*)&A_lds[lrow[q] * LDK + kc4] = pk_bf16x4(areg[q]);
      *(uint2*)&B_lds[lrow[q] * LDK + kc4] = pk_bf16x4(breg[q]);
    }
    __syncthreads();
    if (t + 1 < NT) {
      const float* Ap = (t + 1 < 32) ? X  : Hx;
      const float* Wp = (t + 1 < 32) ? Wx : Wh;
      const int k0 = ((t + 1) & 31) * BK;
      #pragma unroll
      for (int q = 0; q < 8; ++q) {
        areg[q] = *(const float4*)(Ap + aoff[q] + k0);
        breg[q] = *(const float4*)(Wp + boff[q] + k0);
      }
    }
    #pragma unroll
    for (int ks = 0; ks < 2; ++ks) {
      short8 af[4], bfv[4];
      #pragma unroll
      for (int u = 0; u < 4; ++u)
        af[u] = *(const short8*)&A_lds[(wm * 64 + u * 16 + ln) * LDK + ks * 32 + quad * 8];
      #pragma unroll
      for (int u = 0; u < 4; ++u)
        bfv[u] = *(const short8*)&B_lds[(wn * 64 + u * 16 + ln) * LDK + ks * 32 + quad * 8];
      #pragma unroll
      for (int tm = 0; tm < 4; ++tm)
        #pragma unroll
        for (int tn = 0; tn < 4; ++tn)
          acc[tm][tn] = __builtin_amdgcn_mfma_f32_16x16x32_bf16(
              af[tm], bfv[tn], acc[tm][tn], 0, 0, 0);
    }
  }

  const int g = lane & 3;
  float biasv[4];
  int   hgs[4];
  #pragma unroll
  for (int tn = 0; tn < 4; ++tn) {
    int c  = wn * 64 + tn * 16 + ln;
    int hg = h0 + (c >> 2);
    hgs[tn] = hg;
    int j = g * HID + hg;
    biasv[tn] = bx[j] + bh[j];
  }
  #pragma unroll
  for (int tm = 0; tm < 4; ++tm) {
    #pragma unroll
    for (int r = 0; r < 4; ++r) {
      int mrow = m0 + wm * 64 + tm * 16 + quad * 4 + r;
      #pragma unroll
      for (int tn = 0; tn < 4; ++tn) {
        float v   = acc[tm][tn][r] + biasv[tn];
        float act = (g == 2) ? tanhx(v) : sigm(v);
        float y1 = __shfl_xor(act, 1);
        float y2 = __shfl_xor(act, 2);
        float y3 = __shfl_xor(act, 3);
        float ft = (g == 0) ? act : ((g == 1) ? y1 : ((g == 2) ? y2 : y3));
        float it = (g == 1) ? act : ((g == 0) ? y1 : ((g == 3) ? y2 : y3));
        float gt = (g == 2) ? act : ((g == 3) ? y1 : ((g == 0) ? y2 : y3));
        float ot = (g == 3) ? act : ((g == 2) ? y1 : ((g == 1) ? y2 : y3));
        if (g < 2) {
          size_t off = (size_t)mrow * HID + hgs[tn];
          float cxv = Cx[off];
          float cyv = ft * cxv + it * gt;
          if (g == 0) Hy[off] = ot * tanhx(cyv);
          else        Cy[off] = cyv;
        }
      }
    }
  }
}

extern "C" void kernel_launch(void* const* d_in, const int* in_sizes, int n_in,
                              void* d_out, int out_size, void* d_ws, size_t ws_size,
                              hipStream_t stream) {
  const float* X  = (const float*)d_in[0];
  const float* Hx = (const float*)d_in[1];
  const float* Cx = (const float*)d_in[2];
  const float* Wx = (const float*)d_in[3];
  const float* bx = (const float*)d_in[4];
  const float* Wh = (const float*)d_in[5];
  const float* bh = (const float*)d_in[6];
  float*       Hy = (float*)d_out;
  float*       Cy = Hy + (size_t)BATCH * HID;

  const size_t needA = (size_t)BATCH * K4 * sizeof(short);     // 32 MiB
  const size_t needB = (size_t)(4 * HID) * K4 * sizeof(short); // 64 MiB

  if (d_ws != nullptr && ws_size >= needA + needB) {
    short* Abf = (short*)d_ws;
    short* Bbf = (short*)((char*)d_ws + needA);
    conv_a<<<dim3((BATCH * (K4 / 8)) / 256), dim3(256), 0, stream>>>(X, Hx, Abf);
    conv_b<<<dim3((4 * HID * (K4 / 8)) / 256), dim3(256), 0, stream>>>(Wx, Wh, Bbf);
    dim3 grid(BATCH / BM, HID / 32, 1);   // x fastest -> consecutive blocks share B panel
    lstm_mm<<<grid, dim3(256, 1, 1), 0, stream>>>(Abf, Bbf, Cx, bx, bh, Hy, Cy);
  } else {
    dim3 grid(BATCH / BM, HID / 32, 1);
    lstm_cell_fallback<<<grid, dim3(256, 1, 1), 0, stream>>>(X, Hx, Cx, Wx, bx, Wh, bh, Hy, Cy);
  }
}

// Round 2
// 571.727 us; speedup vs baseline: 1.3670x; 1.0249x over previous
//
#include <hip/hip_runtime.h>
#include <hip/hip_bf16.h>

// LSTM cell, R5: 256^2 8-phase GEMM (HK/m201 template in plain HIP).
// (1) conversion passes (unchanged from R4): Acat=bf16([X|Hx]) 4096x4096,
//     Bcat=bf16([Wx|Wh]) 8192x4096 with gate-interleaved rows j'=4h+g.
// (2) lstm_mm8: BM=BN=256, BK=64, 512 thr (8 waves 2Mx4N), 128KiB LDS
//     (2 dbuf x A/B x 256x64 bf16). Per K-tile 4 phases x 16 MFMA; staging
//     via global_load_lds w=16 with pre-swizzled source (XOR slot swizzle,
//     0 bank conflicts in R4); raw s_barrier + counted vmcnt(4@ph4, 6@ph8)
//     keeps 3 half-tiles in flight across barriers; setprio(1) around MFMA.
//     Hazard audit: every LDS region has >=1 phase between last ds_read
//     (drained by lgkmcnt(0) pre-MFMA) and restaging; final iter vmcnt(0).
// Epilogue (bias + sigmoid/tanh + quad-shfl gate exchange) verbatim from R4.

#define BATCH 4096
#define HID   2048
#define KDIM  2048
#define K4    4096
#define LDK   72      // fallback kernel's padded LDS stride

typedef __attribute__((ext_vector_type(8))) short  short8;
typedef __attribute__((ext_vector_type(4))) float  f32x4;

__device__ __forceinline__ float sigm(float x)  { return 1.f / (1.f + __expf(-x)); }
__device__ __forceinline__ float tanhx(float x) { return 2.f / (1.f + __expf(-2.f * x)) - 1.f; }

__device__ __forceinline__ uint2 pk_bf16x4(float4 v) {
  __hip_bfloat162 lo = __float22bfloat162_rn(make_float2(v.x, v.y));
  __hip_bfloat162 hi = __float22bfloat162_rn(make_float2(v.z, v.w));
  uint2 r;
  r.x = *(unsigned*)&lo;
  r.y = *(unsigned*)&hi;
  return r;
}

__device__ __forceinline__ void gload16(const void* g, void* l) {
  __builtin_amdgcn_global_load_lds(
      (const __attribute__((address_space(1))) unsigned int*)g,
      (__attribute__((address_space(3))) unsigned int*)l, 16, 0, 0);
}

#define BAR()  asm volatile("s_barrier" ::: "memory")
#define LGK0() asm volatile("s_waitcnt lgkmcnt(0)" ::: "memory")
#define VMC(n) asm volatile("s_waitcnt vmcnt(" #n ")" ::: "memory")

// ---------------- conversion pass 1: Acat = bf16([X | Hx]) ------------------
__global__ __launch_bounds__(256) void conv_a(const float* __restrict__ X,
                                              const float* __restrict__ Hx,
                                              short* __restrict__ A) {
  const int gid = blockIdx.x * 256 + threadIdx.x;
  const int m   = gid >> 9;
  const int pos = (gid & 511) << 3;
  const float* src = (pos < KDIM) ? X  + (size_t)m * KDIM + pos
                                  : Hx + (size_t)m * KDIM + (pos - KDIM);
  float4 v0 = *(const float4*)src;
  float4 v1 = *(const float4*)(src + 4);
  uint2 p0 = pk_bf16x4(v0), p1 = pk_bf16x4(v1);
  uint4 o; o.x = p0.x; o.y = p0.y; o.z = p1.x; o.w = p1.y;
  *(uint4*)(A + (size_t)gid * 8) = o;
}

// ------ conversion pass 2: Bcat[j'=4h+g][k] = bf16([Wx | Wh][g*2048+h]) -----
__global__ __launch_bounds__(256) void conv_b(const float* __restrict__ Wx,
                                              const float* __restrict__ Wh,
                                              short* __restrict__ Bm) {
  const int gid = blockIdx.x * 256 + threadIdx.x;
  const int jp  = gid >> 9;
  const int pos = (gid & 511) << 3;
  const int srow = (jp & 3) * HID + (jp >> 2);
  const float* src = (pos < KDIM) ? Wx + (size_t)srow * KDIM + pos
                                  : Wh + (size_t)srow * KDIM + (pos - KDIM);
  float4 v0 = *(const float4*)src;
  float4 v1 = *(const float4*)(src + 4);
  uint2 p0 = pk_bf16x4(v0), p1 = pk_bf16x4(v1);
  uint4 o; o.x = p0.x; o.y = p0.y; o.z = p1.x; o.w = p1.y;
  *(uint4*)(Bm + (size_t)gid * 8) = o;
}

// ---------------- helpers for the 8-phase kernel ----------------------------
__device__ __forceinline__ void lda4(short8 (&dst)[8], const short* base,
                                     int arow, int sx0, int sx1, int mfb) {
  #pragma unroll
  for (int u = 0; u < 4; ++u) {
    dst[u]     = *(const short8*)&base[arow + (mfb + u) * 1024 + sx0];
    dst[4 + u] = *(const short8*)&base[arow + (mfb + u) * 1024 + sx1];
  }
}
__device__ __forceinline__ void ldb2(short8 (&dst)[4], const short* base,
                                     int brow, int sx0, int sx1, int nfb) {
  #pragma unroll
  for (int v = 0; v < 2; ++v) {
    dst[v]     = *(const short8*)&base[brow + (nfb + v) * 1024 + sx0];
    dst[2 + v] = *(const short8*)&base[brow + (nfb + v) * 1024 + sx1];
  }
}
__device__ __forceinline__ void mmq(f32x4 (&acc)[8][4], const short8 (&A)[8],
                                    const short8 (&B)[4], int MB, int NB) {
  __builtin_amdgcn_s_setprio(1);
  #pragma unroll
  for (int ks = 0; ks < 2; ++ks)
    #pragma unroll
    for (int u = 0; u < 4; ++u)
      #pragma unroll
      for (int v = 0; v < 2; ++v)
        acc[MB + u][NB + v] = __builtin_amdgcn_mfma_f32_16x16x32_bf16(
            A[ks * 4 + u], B[ks * 2 + v], acc[MB + u][NB + v], 0, 0, 0);
  __builtin_amdgcn_s_setprio(0);
}

// ---------------- main GEMM + LSTM epilogue (256^2, 8-phase) ----------------
__global__ __launch_bounds__(512, 2) void lstm_mm8(
    const short* __restrict__ A, const short* __restrict__ Bm,
    const float* __restrict__ Cx,
    const float* __restrict__ bx, const float* __restrict__ bh,
    float* __restrict__ Hy, float* __restrict__ Cy)
{
  __shared__ __align__(16) short A_sh[2 * 16384];  // [d][256 rows][64], 64 KiB
  __shared__ __align__(16) short B_sh[2 * 16384];  // [d][256 rows][64], 64 KiB

  const int tid  = threadIdx.x;
  const int wv   = tid >> 6;         // 0..7
  const int lane = tid & 63;
  const int quad = lane >> 4;
  const int ln   = lane & 15;
  const int wm   = wv >> 2;          // 2 waves in M
  const int wn   = wv & 3;           // 4 waves in N
  const int m0   = blockIdx.x * 256;
  const int j0   = blockIdx.y * 256; // = 4 * h0
  const int h0   = blockIdx.y * 64;

  f32x4 acc[8][4];
  #pragma unroll
  for (int a = 0; a < 8; ++a)
    #pragma unroll
    for (int b = 0; b < 4; ++b)
      acc[a][b] = (f32x4){0.f, 0.f, 0.f, 0.f};

  // staging: per wave, one half-tile (128x64) = 2 gload16 issues (16 rows of
  // wave's slice). chunk c = wv*2+i covers rows c*8..c*8+7; LDS dest linear,
  // global source pre-swizzled: slot^row&7.
  const int l8  = lane >> 3;
  const int swz = ((lane & 7) ^ (l8 & 7)) << 3;
  const short* aG = A  + (size_t)(m0 + l8) * K4 + swz;
  const short* bG = Bm + (size_t)(j0 + l8) * K4 + swz;

  #define STAGE_A(d, h, tau) do {                                             \
    gload16(aG + ((size_t)((h)*128 + wv*16    )) * K4 + (tau)*64,             \
            &A_sh[(d)*16384 + (h)*8192 + wv*1024]);                           \
    gload16(aG + ((size_t)((h)*128 + wv*16 + 8)) * K4 + (tau)*64,             \
            &A_sh[(d)*16384 + (h)*8192 + wv*1024 + 512]);                     \
  } while (0)
  #define STAGE_B(d, h, tau) do {                                             \
    gload16(bG + ((size_t)((h)*128 + wv*16    )) * K4 + (tau)*64,             \
            &B_sh[(d)*16384 + (h)*8192 + wv*1024]);                           \
    gload16(bG + ((size_t)((h)*128 + wv*16 + 8)) * K4 + (tau)*64,             \
            &B_sh[(d)*16384 + (h)*8192 + wv*1024 + 512]);                     \
  } while (0)

  // ds_read geometry (identical swizzle as R4; measured 0 bank conflicts)
  const int arow = (wm * 128 + ln) * 64;   // shorts
  const int brow = (wn * 64  + ln) * 64;
  const int sx0  = ((0 + quad) ^ (ln & 7)) << 3;
  const int sx1  = ((4 + quad) ^ (ln & 7)) << 3;

  // prologue: tile0 -> dbuf0 (4 halves), tile1 -> dbuf1 (3 halves; B-h1 of
  // tile1 is staged at ph1 of iteration 0). 14 loads; vmcnt(6) => tile0 done.
  STAGE_A(0, 0, 0); STAGE_A(0, 1, 0); STAGE_B(0, 0, 0); STAGE_B(0, 1, 0);
  STAGE_A(1, 0, 1); STAGE_A(1, 1, 1); STAGE_B(1, 0, 1);
  VMC(6);
  BAR();

  short8 aQ0[8], aQ1[8], bLo[4], bHi[4];

  #pragma unroll 1
  for (int i = 0; i < 32; ++i) {
    const int  S0 = 2 * i + 2, S1 = 2 * i + 3, T1k = 2 * i + 1;
    const bool nl = (i != 31);
    // ---- ph1: read A(mf0-3)+B(nf0-1) of dbuf0; stage dbuf1.B-h1 <- T1 ----
    lda4(aQ0, &A_sh[0], arow, sx0, sx1, 0);
    ldb2(bLo, &B_sh[0], brow, sx0, sx1, 0);
    STAGE_B(1, 1, T1k);
    BAR(); LGK0();
    mmq(acc, aQ0, bLo, 0, 0);
    BAR();
    // ---- ph2: read A(mf4-7) dbuf0 ----------------------------------------
    lda4(aQ1, &A_sh[0], arow, sx0, sx1, 4);
    BAR(); LGK0();
    mmq(acc, aQ1, bLo, 4, 0);
    BAR();
    // ---- ph3: read B(nf2-3) dbuf0; stage dbuf0.A-h0 <- S0 ----------------
    ldb2(bHi, &B_sh[0], brow, sx0, sx1, 2);
    if (nl) STAGE_A(0, 0, S0);
    BAR(); LGK0();
    mmq(acc, aQ1, bHi, 4, 2);
    BAR();
    // ---- ph4: stage dbuf0.B-h0 <- S0; vmcnt(4) => dbuf1 tile T1 landed ---
    if (nl) STAGE_B(0, 0, S0);
    BAR();
    mmq(acc, aQ0, bHi, 0, 2);
    if (nl) { VMC(4); } else { VMC(0); }
    BAR();
    // ---- ph5: read A(mf0-3)+B(nf0-1) of dbuf1; stage dbuf0.A-h1 ----------
    lda4(aQ0, &A_sh[16384], arow, sx0, sx1, 0);
    ldb2(bLo, &B_sh[16384], brow, sx0, sx1, 0);
    if (nl) STAGE_A(0, 1, S0);
    BAR(); LGK0();
    mmq(acc, aQ0, bLo, 0, 0);
    BAR();
    // ---- ph6: read A(mf4-7) dbuf1; stage dbuf0.B-h1 ----------------------
    lda4(aQ1, &A_sh[16384], arow, sx0, sx1, 4);
    if (nl) STAGE_B(0, 1, S0);
    BAR(); LGK0();
    mmq(acc, aQ1, bLo, 4, 0);
    BAR();
    // ---- ph7: read B(nf2-3) dbuf1; stage dbuf1.A-h0 <- S1 ----------------
    ldb2(bHi, &B_sh[16384], brow, sx0, sx1, 2);
    if (nl) STAGE_A(1, 0, S1);
    BAR(); LGK0();
    mmq(acc, aQ1, bHi, 4, 2);
    BAR();
    // ---- ph8: stage dbuf1.B-h0 + dbuf1.A-h1 <- S1; vmcnt(6) --------------
    if (nl) { STAGE_B(1, 0, S1); STAGE_A(1, 1, S1); }
    BAR();
    mmq(acc, aQ0, bHi, 0, 2);
    if (nl) { VMC(6); }
    BAR();
  }
  #undef STAGE_A
  #undef STAGE_B

  // ---- epilogue: C/D layout col = lane&15 (c), row = quad*4 + reg ----
  const int g = lane & 3;            // gate of this lane (c&3)
  float biasv[4];
  int   hgs[4];
  #pragma unroll
  for (int nf = 0; nf < 4; ++nf) {
    int c  = wn * 64 + nf * 16 + ln;
    int hg = h0 + (c >> 2);
    hgs[nf] = hg;
    int j = g * HID + hg;
    biasv[nf] = bx[j] + bh[j];
  }
  #pragma unroll
  for (int mf = 0; mf < 8; ++mf) {
    #pragma unroll
    for (int r = 0; r < 4; ++r) {
      int mrow = m0 + wm * 128 + mf * 16 + quad * 4 + r;
      #pragma unroll
      for (int nf = 0; nf < 4; ++nf) {
        float v   = acc[mf][nf][r] + biasv[nf];
        float act = (g == 2) ? tanhx(v) : sigm(v);
        float y1 = __shfl_xor(act, 1);
        float y2 = __shfl_xor(act, 2);
        float y3 = __shfl_xor(act, 3);
        float ft = (g == 0) ? act : ((g == 1) ? y1 : ((g == 2) ? y2 : y3));
        float it = (g == 1) ? act : ((g == 0) ? y1 : ((g == 3) ? y2 : y3));
        float gt = (g == 2) ? act : ((g == 3) ? y1 : ((g == 0) ? y2 : y3));
        float ot = (g == 3) ? act : ((g == 2) ? y1 : ((g == 1) ? y2 : y3));
        if (g < 2) {
          size_t off = (size_t)mrow * HID + hgs[nf];
          float cxv = Cx[off];
          float cyv = ft * cxv + it * gt;
          if (g == 0) Hy[off] = ot * tanhx(cyv);
          else        Cy[off] = cyv;
        }
      }
    }
  }
}

// ---------------- fallback: R3 kernel (register staging, fp32 in) ----------
__global__ __launch_bounds__(256) void lstm_cell_fallback(
    const float* __restrict__ X, const float* __restrict__ Hx,
    const float* __restrict__ Cx,
    const float* __restrict__ Wx, const float* __restrict__ bx,
    const float* __restrict__ Wh, const float* __restrict__ bh,
    float* __restrict__ Hy, float* __restrict__ Cy)
{
  __shared__ __align__(16) short A_lds[128 * LDK];
  __shared__ __align__(16) short B_lds[128 * LDK];

  const int tid  = threadIdx.x;
  const int wv   = tid >> 6;
  const int lane = tid & 63;
  const int quad = lane >> 4;
  const int ln   = lane & 15;
  const int wm   = wv >> 1;
  const int wn   = wv & 1;
  const int m0   = blockIdx.x * 128;
  const int h0   = blockIdx.y * 32;

  f32x4 acc[4][4];
  #pragma unroll
  for (int a = 0; a < 4; ++a)
    #pragma unroll
    for (int b = 0; b < 4; ++b)
      acc[a][b] = (f32x4){0.f, 0.f, 0.f, 0.f};

  const int rA  = tid >> 4;
  const int kc4 = (tid & 15) * 4;
  size_t aoff[8], boff[8];
  int    lrow[8];
  #pragma unroll
  for (int q = 0; q < 8; ++q) {
    int row  = q * 16 + rA;
    lrow[q]  = row;
    aoff[q]  = (size_t)(m0 + row) * KDIM + kc4;
    int wrow = (row & 3) * HID + h0 + (row >> 2);
    boff[q]  = (size_t)wrow * KDIM + kc4;
  }

  const int NT = 2 * (KDIM / 64);
  float4 areg[8], breg[8];
  #pragma unroll
  for (int q = 0; q < 8; ++q) {
    areg[q] = *(const float4*)(X  + aoff[q]);
    breg[q] = *(const float4*)(Wx + boff[q]);
  }

  for (int t = 0; t < NT; ++t) {
    __syncthreads();
    #pragma unroll
    for (int q = 0; q < 8; ++q) {
      *(uint2*)&A_lds[lrow[q] * LDK + kc4] = pk_bf16x4(areg[q]);
      *(uint2*)&B_lds[lrow[q] * LDK + kc4] = pk_bf16x4(breg[q]);
    }
    __syncthreads();
    if (t + 1 < NT) {
      const float* Ap = (t + 1 < 32) ? X  : Hx;
      const float* Wp = (t + 1 < 32) ? Wx : Wh;
      const int k0 = ((t + 1) & 31) * 64;
      #pragma unroll
      for (int q = 0; q < 8; ++q) {
        areg[q] = *(const float4*)(Ap + aoff[q] + k0);
        breg[q] = *(const float4*)(Wp + boff[q] + k0);
      }
    }
    #pragma unroll
    for (int ks = 0; ks < 2; ++ks) {
      short8 af[4], bfv[4];
      #pragma unroll
      for (int u = 0; u < 4; ++u)
        af[u] = *(const short8*)&A_lds[(wm * 64 + u * 16 + ln) * LDK + ks * 32 + quad * 8];
      #pragma unroll
      for (int u = 0; u < 4; ++u)
        bfv[u] = *(const short8*)&B_lds[(wn * 64 + u * 16 + ln) * LDK + ks * 32 + quad * 8];
      #pragma unroll
      for (int tm = 0; tm < 4; ++tm)
        #pragma unroll
        for (int tn = 0; tn < 4; ++tn)
          acc[tm][tn] = __builtin_amdgcn_mfma_f32_16x16x32_bf16(
              af[tm], bfv[tn], acc[tm][tn], 0, 0, 0);
    }
  }

  const int g = lane & 3;
  float biasv[4];
  int   hgs[4];
  #pragma unroll
  for (int tn = 0; tn < 4; ++tn) {
    int c  = wn * 64 + tn * 16 + ln;
    int hg = h0 + (c >> 2);
    hgs[tn] = hg;
    int j = g * HID + hg;
    biasv[tn] = bx[j] + bh[j];
  }
  #pragma unroll
  for (int tm = 0; tm < 4; ++tm) {
    #pragma unroll
    for (int r = 0; r < 4; ++r) {
      int mrow = m0 + wm * 64 + tm * 16 + quad * 4 + r;
      #pragma unroll
      for (int tn = 0; tn < 4; ++tn) {
        float v   = acc[tm][tn][r] + biasv[tn];
        float act = (g == 2) ? tanhx(v) : sigm(v);
        float y1 = __shfl_xor(act, 1);
        float y2 = __shfl_xor(act, 2);
        float y3 = __shfl_xor(act, 3);
        float ft = (g == 0) ? act : ((g == 1) ? y1 : ((g == 2) ? y2 : y3));
        float it = (g == 1) ? act : ((g == 0) ? y1 : ((g == 3) ? y2 : y3));
        float gt = (g == 2) ? act : ((g == 3) ? y1 : ((g == 0) ? y2 : y3));
        float ot = (g == 3) ? act : ((g == 2) ? y1 : ((g == 1) ? y2 : y3));
        if (g < 2) {
          size_t off = (size_t)mrow * HID + hgs[tn];
          float cxv = Cx[off];
          float cyv = ft * cxv + it * gt;
          if (g == 0) Hy[off] = ot * tanhx(cyv);
          else        Cy[off] = cyv;
        }
      }
    }
  }
}

extern "C" void kernel_launch(void* const* d_in, const int* in_sizes, int n_in,
                              void* d_out, int out_size, void* d_ws, size_t ws_size,
                              hipStream_t stream) {
  const float* X  = (const float*)d_in[0];
  const float* Hx = (const float*)d_in[1];
  const float* Cx = (const float*)d_in[2];
  const float* Wx = (const float*)d_in[3];
  const float* bx = (const float*)d_in[4];
  const float* Wh = (const float*)d_in[5];
  const float* bh = (const float*)d_in[6];
  float*       Hy = (float*)d_out;
  float*       Cy = Hy + (size_t)BATCH * HID;

  const size_t needA = (size_t)BATCH * K4 * sizeof(short);     // 32 MiB
  const size_t needB = (size_t)(4 * HID) * K4 * sizeof(short); // 64 MiB

  if (d_ws != nullptr && ws_size >= needA + needB) {
    short* Abf = (short*)d_ws;
    short* Bbf = (short*)((char*)d_ws + needA);
    conv_a<<<dim3((BATCH * (K4 / 8)) / 256), dim3(256), 0, stream>>>(X, Hx, Abf);
    conv_b<<<dim3((4 * HID * (K4 / 8)) / 256), dim3(256), 0, stream>>>(Wx, Wh, Bbf);
    dim3 grid(BATCH / 256, (4 * HID) / 256, 1);  // 16 x 32; x fastest -> B-panel reuse
    lstm_mm8<<<grid, dim3(512, 1, 1), 0, stream>>>(Abf, Bbf, Cx, bx, bh, Hy, Cy);
  } else {
    dim3 grid(BATCH / 128, HID / 32, 1);
    lstm_cell_fallback<<<grid, dim3(256, 1, 1), 0, stream>>>(X, Hx, Cx, Wx, bx, Wh, bh, Hy, Cy);
  }
}